// Round 4
// baseline (256.739 us; speedup 1.0000x reference)
//
#include <hip/hip_runtime.h>
#include <math.h>

// Round 10: 3-wave balanced pipeline. Round 9 proved the kernel is
// issue-packing-bound: single wave = 33% packing (latency), round 8's 2-wave
// = imbalanced (65 vs 45 instr/step). New split, ~balanced:
//   role 0: encoder (4 ballots) + decoder scan + deferred stores
//           (all t-sequential state: ve, v, i_syn)
//   role 1: conv-LUT + linear for even t   } each t computed entirely
//   role 2: conv-LUT + linear for odd  t   } within one wave (s_p private)
// 2048 blocks x 3 waves = 24 waves/CU (6/SIMD), +50% TLP vs round 8.
// Roles staggered by (wv + blockIdx)%3 so heavy waves spread over SIMDs.
// Barrier every 4 steps; s_bits/s_lin 8-deep so producer/consumer touch
// disjoint halves between barriers:
//   group g: enc writes bits slots (4g..4g+3)&7; conv reads (4g-4..4g-1)&7,
//            writes lin slots (4g-4..4g-1)&7; dec reads (4g-8..4g-5)&7;
//            stores issue for steps 4g-12..4g-9 (round 8's drain trick).
// All FP chains byte-identical to rounds 8/9. Requires T%4==0, T>=12.

typedef float v2f __attribute__((ext_vector_type(2)));

__global__ __launch_bounds__(192, 6) void snn_step_kernel(
    const float* __restrict__ x,       // [B,1,15,15]
    const float* __restrict__ conv_w,  // [2,1,4,4]
    const float* __restrict__ conv_b,  // [2]
    const float* __restrict__ lin_w,   // [10,72]
    const float* __restrict__ lin_b,   // [10]
    float* __restrict__ out,           // spk_out[B,10] ++ mem_rec[T,B,10] ++ spk_rec[T,B,10]
    int T, int B)
{
    const int b    = blockIdx.x;
    const int tid  = threadIdx.x;
    const int w    = tid & 63;
    const int wv   = tid >> 6;            // 0..2
    const int role = (wv + b) % 3;        // 0: enc+dec, 1: conv+lin even t, 2: odd t

    __shared__ float    s_linw[720];
    __shared__ float    s_linb[10];
    __shared__ float4   s_lut[4][32];     // [ky][5-bit row bits] -> 4 partial sums
    __shared__ unsigned s_bits[8][16];    // 8-deep packed spike rows
    __shared__ float    s_lin[8][12];     // 8-deep lin outputs (pad 10->12)
    __shared__ float    s_p[2][80];       // per conv-wave private (4 chunks x 20)
    __shared__ float    s_part[2][64];    // per conv-wave private

    // ---- cooperative staging (192 threads) ----
    for (int j = tid; j < 720; j += 192) s_linw[j] = lin_w[j];
    if (tid < 10) s_linb[tid] = lin_b[tid];
    if (tid < 128) {
        const int ky = tid >> 5, n = tid & 31;
        float s00 = 0.f, s01 = 0.f, s10 = 0.f, s11 = 0.f;
#pragma unroll
        for (int kx = 0; kx < 4; ++kx) {
            const float w0 = conv_w[ky * 4 + kx];        // ch0
            const float w1 = conv_w[16 + ky * 4 + kx];   // ch1
            if ((n >> kx) & 1)       { s00 += w0; s01 += w1; }  // dx = 0
            if ((n >> (kx + 1)) & 1) { s10 += w0; s11 += w1; }  // dx = 1
        }
        s_lut[ky][n] = make_float4(s00, s01, s10, s11);
    }
    __syncthreads();

    // ===== role-0 state (encoder + decoder) =====
    float ve[4], cur[4];
    float v = 0.f, i_syn = 0.f, sc = 0.f;
    float svv[4], svs[4];
    const size_t BO = (size_t)B * 10;
    float* mp  = out + BO + (size_t)b * 10 + w;
    float* spp = out + BO + (size_t)T * BO + (size_t)b * 10 + w;
    {
        const int jrow = w >> 4, col = w & 15;
#pragma unroll
        for (int k = 0; k < 4; ++k) {
            const int  row = 4 * k + jrow;
            const bool act = (col < 15) && (row < 15) && (role == 0);
            ve[k]  = 0.f;
            cur[k] = act ? __fmul_rn(x[(size_t)b * 225 + row * 15 + col], 10.0f) : 0.f;
        }
    }

    // ===== conv/lin lane params (roles 1,2) =====
    const int  r1 = (role == 2) ? 1 : 0;     // private buffer index
    const bool convlane = (w < 36);
    const int  py = w / 6, px = w - 6 * py;
    const int  wordsel = py;                 // words py..py+2 hold rows 2py..2py+5
    const int  shx = 2 * px, shx16 = shx + 16;
    const int  off0 = (w < 18) ? w : (w + 2);
    const v2f  cb2 = (v2f){conv_b[0], conv_b[1]};
    const int  lo = w >> 2, lq = w & 3;
    float lwreg[18];
#pragma unroll
    for (int jj = 0; jj < 18; ++jj) {
        int idx = lo * 72 + lq * 18 + jj;
        lwreg[jj] = s_linw[idx < 720 ? idx : 719];
    }
    const float lbias = (w < 10) ? s_linb[w] : 0.f;

    // encoder step (all 64 lanes) + ballot bit-pack -> s_bits[slot]
    auto enc_pack = [&](int slot) {
        unsigned long long bal0, bal1, bal2, bal3;
        {
            float vn = __fadd_rn(ve[0], __fmul_rn(0.1f, __fsub_rn(cur[0], ve[0])));
            bool  sp = (vn > 1.0f);
            ve[0] = sp ? 0.f : vn;
            bal0  = __ballot(sp);
        }
        {
            float vn = __fadd_rn(ve[1], __fmul_rn(0.1f, __fsub_rn(cur[1], ve[1])));
            bool  sp = (vn > 1.0f);
            ve[1] = sp ? 0.f : vn;
            bal1  = __ballot(sp);
        }
        {
            float vn = __fadd_rn(ve[2], __fmul_rn(0.1f, __fsub_rn(cur[2], ve[2])));
            bool  sp = (vn > 1.0f);
            ve[2] = sp ? 0.f : vn;
            bal2  = __ballot(sp);
        }
        {
            float vn = __fadd_rn(ve[3], __fmul_rn(0.1f, __fsub_rn(cur[3], ve[3])));
            bool  sp = (vn > 1.0f);
            ve[3] = sp ? 0.f : vn;
            bal3  = __ballot(sp);
        }
        // masks are wave-uniform; lanes 0..7 pick their 32-bit word
        unsigned long long m01 = (w & 2) ? bal1 : bal0;
        unsigned long long m23 = (w & 2) ? bal3 : bal2;
        unsigned long long m   = (w & 4) ? m23 : m01;
        unsigned word = (unsigned)((w & 1) ? (m >> 32) : m);
        if (w < 8) s_bits[slot][w] = word;
    };

    // conv-LUT + linear for step t, entirely within this wave -> s_lin[t&7]
    auto conv_lin = [&](int t) {
        const int slot = t & 7;
        if (convlane) {
            const unsigned* bb = &s_bits[slot][wordsel];
            const unsigned wb0 = bb[0], wb1 = bb[1], wb2 = bb[2];

            const int i0 = (wb0 >> shx)   & 31;
            const int i1 = (wb0 >> shx16) & 31;
            const int i2 = (wb1 >> shx)   & 31;
            const int i3 = (wb1 >> shx16) & 31;
            const int i4 = (wb2 >> shx)   & 31;

            const float4 f0 = s_lut[0][i0];
            const float4 f1 = s_lut[1][i1];
            const float4 f2 = s_lut[2][i2];
            const float4 f3 = s_lut[3][i3];
            const float4 g0 = s_lut[0][i1];
            const float4 g1 = s_lut[1][i2];
            const float4 g2 = s_lut[2][i3];
            const float4 g3 = s_lut[3][i4];

            v2f a00 = (v2f){f0.x, f0.y};  a00 += (v2f){f1.x, f1.y};
            a00 += (v2f){f2.x, f2.y};     a00 += (v2f){f3.x, f3.y};
            v2f a01 = (v2f){f0.z, f0.w};  a01 += (v2f){f1.z, f1.w};
            a01 += (v2f){f2.z, f2.w};     a01 += (v2f){f3.z, f3.w};
            v2f a10 = (v2f){g0.x, g0.y};  a10 += (v2f){g1.x, g1.y};
            a10 += (v2f){g2.x, g2.y};     a10 += (v2f){g3.x, g3.y};
            v2f a11 = (v2f){g0.z, g0.w};  a11 += (v2f){g1.z, g1.w};
            a11 += (v2f){g2.z, g2.w};     a11 += (v2f){g3.z, g3.w};

            v2f v00 = a00 + cb2, v01 = a01 + cb2;
            v2f v10 = a10 + cb2, v11 = a11 + cb2;
            v2f m2 = __builtin_elementwise_max(
                         __builtin_elementwise_max(v00, v01),
                         __builtin_elementwise_max(v10, v11));

            float* pbuf = s_p[r1];
            pbuf[off0]      = m2.x;   // p[w]
            pbuf[off0 + 40] = m2.y;   // p[36 + w]
        }
        asm volatile("" ::: "memory");   // keep LDS write -> read ordered

        float pv[18];
        {
            const float* pp = &s_p[r1][lq * 20];
#pragma unroll
            for (int jj = 0; jj < 18; ++jj) pv[jj] = pp[jj];
        }
        float partial = 0.0f;
#pragma unroll
        for (int jj = 0; jj < 18; ++jj)
            partial = fmaf(lwreg[jj], pv[jj], partial);
        s_part[r1][w] = partial;
        asm volatile("" ::: "memory");

        float4 pr = *(const float4*)&s_part[r1][4 * (w < 10 ? w : 0)];
        float lin = __fadd_rn(__fadd_rn(__fadd_rn(__fadd_rn(pr.x, pr.y), pr.z), pr.w), lbias);
        if (w < 10) s_lin[slot][w] = lin;
    };

    // decoder step t (state chain identical to rounds 8/9); k = defer slot
    const int li = (w < 10) ? w : 10;
    auto dec_step = [&](int t, int k) {
        float lv  = s_lin[t & 7][li];
        float vd  = __fadd_rn(v, __fmul_rn(0.1f, __fsub_rn(i_syn, v)));
        float id  = __fsub_rn(i_syn, __fmul_rn(0.2f, i_syn));
        float spk = (vd > 1.0f) ? 1.0f : 0.0f;
        v = (vd > 1.0f) ? 0.0f : vd;
        sc += spk;
        svv[k] = v;
        svs[k] = spk;
        i_syn = __fadd_rn(id, lv);
    };

    auto issue_stores = [&]() {
        if (w < 10) {
#pragma unroll
            for (int k = 0; k < 4; ++k) {
                mp[(size_t)k * BO]  = svv[k];
                spp[(size_t)k * BO] = svs[k];
            }
        }
        mp  += 4 * BO;
        spp += 4 * BO;
    };

    const int NG = T >> 2;   // T % 4 == 0; T >= 12

    for (int g = 0; g < NG; ++g) {
        const int base = 4 * g;
        if (role == 0) {
            if (g >= 3) issue_stores();                 // steps base-12..base-9
#pragma unroll
            for (int k = 0; k < 4; ++k)                 // enc steps base..base+3
                enc_pack((base + k) & 7);
            if (g >= 2) {
#pragma unroll
                for (int k = 0; k < 4; ++k)             // dec steps base-8..base-5
                    dec_step(base - 8 + k, k);
            }
        } else {
            if (g >= 1) {
                for (int k = role - 1; k < 4; k += 2)   // conv+lin steps base-4..base-1
                    conv_lin(base - 4 + k);             // (parity = role-1)
            }
        }
        __syncthreads();
    }

    // ---- epilogue ----
    // phase A: conv waves do steps T-4..T-1 (lin slots (T-4..T-1)&7 = 0..3);
    //          role0 reads disjoint slots 4..7 (steps T-8..T-5) - no race.
    if (role != 0) {
        for (int k = role - 1; k < 4; k += 2)
            conv_lin(T - 4 + k);
    } else {
        issue_stores();                                 // steps T-12..T-9
#pragma unroll
        for (int k = 0; k < 4; ++k)                     // dec steps T-8..T-5
            dec_step(T - 8 + k, k);
    }
    __syncthreads();
    if (role == 0) {
        issue_stores();                                 // steps T-8..T-5
#pragma unroll
        for (int k = 0; k < 4; ++k)                     // dec steps T-4..T-1
            dec_step(T - 4 + k, k);
        issue_stores();                                 // steps T-4..T-1
        if (w < 10) out[(size_t)b * 10 + w] = sc;
    }
}

extern "C" void kernel_launch(void* const* d_in, const int* in_sizes, int n_in,
                              void* d_out, int out_size, void* d_ws, size_t ws_size,
                              hipStream_t stream) {
    const float* x      = (const float*)d_in[0];
    const float* conv_w = (const float*)d_in[1];
    const float* conv_b = (const float*)d_in[2];
    const float* lin_w  = (const float*)d_in[3];
    const float* lin_b  = (const float*)d_in[4];
    float* out = (float*)d_out;

    const int B = in_sizes[0] / 225;             // x is [B,1,15,15]
    const int T = (out_size / (B * 10) - 1) / 2; // out = B*10 * (1 + 2T); T=300

    snn_step_kernel<<<B, 192, 0, stream>>>(x, conv_w, conv_b, lin_w, lin_b, out, T, B);
}

// Round 5
// 198.339 us; speedup vs baseline: 1.2944x; 1.2944x over previous
//
#include <hip/hip_runtime.h>
#include <math.h>

// Round 11: R8's two-wave pipeline (best: 146us), rebalanced + trimmed.
//   - G=6 steps per barrier (T=300=6*50; barriers 75->50). s_bits/s_p 16-deep;
//     concurrent slot windows are <=12 consecutive values mod 16 -> disjoint:
//       wave0 writes bits {6g+1..6g+6}&15, s_p {6g..6g+3}&15
//       wave1 reads  bits {6g-2,6g-1}&15, s_p {6g-6..6g-1}&15,
//             writes s_p {6g-2,6g-1}&15        (offsets {14,15} vs {0..3})
//   - conv split 4+2: wave0 = 6 enc + 4 conv (~378 issue-cyc/group),
//     wave1 = 2 conv + 6 lin+dec + stores (~345) -- vs R8's 520/340 imbalance.
//     wave1's conv reads bits written by wave0 one group earlier (barrier-safe),
//     writes s_p slots it then reads in-wave (in-order DS).
//   - linear reduce via 3x __shfl_xor (masks 1,2,3) summed in the EXACT
//     original order (((p0+p1)+p2)+p3)+lbias on lq==0 lanes -> s_part LDS
//     round trip deleted. Decoder replicated per-quad; only lq==0&&lo<10
//     lanes store (byte-identical values).
//   - stores deferred 2 groups (R8's vmcnt-drain trick), svv/svs[6].
// Encoder / conv-LUT / 18-fma / decoder FP chains byte-identical to R8.
// Requires T % 6 == 0, T >= 18.

typedef float v2f __attribute__((ext_vector_type(2)));

__global__ __launch_bounds__(128, 4) void snn_step_kernel(
    const float* __restrict__ x,       // [B,1,15,15]
    const float* __restrict__ conv_w,  // [2,1,4,4]
    const float* __restrict__ conv_b,  // [2]
    const float* __restrict__ lin_w,   // [10,72]
    const float* __restrict__ lin_b,   // [10]
    float* __restrict__ out,           // spk_out[B,10] ++ mem_rec[T,B,10] ++ spk_rec[T,B,10]
    int T, int B)
{
    const int b   = blockIdx.x;
    const int tid = threadIdx.x;
    const int w   = tid & 63;
    const int wv  = tid >> 6;   // 0 = enc + 4conv, 1 = 2conv + lin + dec

    __shared__ float    s_linw[720];
    __shared__ float    s_linb[10];
    __shared__ float4   s_lut[4][32];   // [ky][5-bit row bits] -> 4 partial sums
    __shared__ unsigned s_bits[16][8];  // 16-deep packed spike rows (8 words used)
    __shared__ float    s_p[16][80];    // 16-deep pooled outputs (4 chunks x 20)

    // ---- cooperative staging (128 threads) ----
    for (int j = tid; j < 720; j += 128) s_linw[j] = lin_w[j];
    if (tid < 10) s_linb[tid] = lin_b[tid];
    {
        const int ky = tid >> 5, n = tid & 31;
        float s00 = 0.f, s01 = 0.f, s10 = 0.f, s11 = 0.f;
#pragma unroll
        for (int kx = 0; kx < 4; ++kx) {
            const float w0 = conv_w[ky * 4 + kx];        // ch0
            const float w1 = conv_w[16 + ky * 4 + kx];   // ch1
            if ((n >> kx) & 1)       { s00 += w0; s01 += w1; }  // dx = 0
            if ((n >> (kx + 1)) & 1) { s10 += w0; s11 += w1; }  // dx = 1
        }
        s_lut[ky][n] = make_float4(s00, s01, s10, s11);
    }
    __syncthreads();

    // ===== encoder state (wave0 only; wave1 lanes hold zeros) =====
    float ve[4], cur[4];
    {
        const int jrow = w >> 4, col = w & 15;
#pragma unroll
        for (int k = 0; k < 4; ++k) {
            const int  row = 4 * k + jrow;
            const bool act = (col < 15) && (row < 15) && (wv == 0);
            ve[k]  = 0.f;
            cur[k] = act ? __fmul_rn(x[(size_t)b * 225 + row * 15 + col], 10.0f) : 0.f;
        }
    }

    // ===== conv lane params (used by both waves) =====
    const bool convlane = (w < 36);
    const int  py = w / 6, px = w - 6 * py;
    const int  wordsel = py;                 // words py..py+2 hold rows 2py..2py+5
    const int  shx = 2 * px, shx16 = shx + 16;
    const int  off0 = (w < 18) ? w : (w + 2);
    const v2f  cb2 = (v2f){conv_b[0], conv_b[1]};

    // ===== lin/decoder lane params (wave1) =====
    const int lo = w >> 2, lq = w & 3;
    float lwreg[18];
#pragma unroll
    for (int jj = 0; jj < 18; ++jj) {
        int idx = lo * 72 + lq * 18 + jj;
        lwreg[jj] = s_linw[idx < 720 ? idx : 719];   // clamp for lanes >= 40
    }
    const float lbias = s_linb[lo < 10 ? lo : 0];
    float v = 0.f, i_syn = 0.f, sc = 0.f;
    float svv[6], svs[6];
    const size_t BO = (size_t)B * 10;
    float* mp  = out + BO + (size_t)b * 10 + lo;
    float* spp = out + BO + (size_t)T * BO + (size_t)b * 10 + lo;

    // encoder step (all 64 lanes of wave0) + ballot bit-pack -> s_bits[slot]
    auto enc_pack = [&](int slot) {
        unsigned long long bal0, bal1, bal2, bal3;
        {
            float vn = __fadd_rn(ve[0], __fmul_rn(0.1f, __fsub_rn(cur[0], ve[0])));
            bool  sp = (vn > 1.0f);
            ve[0] = sp ? 0.f : vn;
            bal0  = __ballot(sp);
        }
        {
            float vn = __fadd_rn(ve[1], __fmul_rn(0.1f, __fsub_rn(cur[1], ve[1])));
            bool  sp = (vn > 1.0f);
            ve[1] = sp ? 0.f : vn;
            bal1  = __ballot(sp);
        }
        {
            float vn = __fadd_rn(ve[2], __fmul_rn(0.1f, __fsub_rn(cur[2], ve[2])));
            bool  sp = (vn > 1.0f);
            ve[2] = sp ? 0.f : vn;
            bal2  = __ballot(sp);
        }
        {
            float vn = __fadd_rn(ve[3], __fmul_rn(0.1f, __fsub_rn(cur[3], ve[3])));
            bool  sp = (vn > 1.0f);
            ve[3] = sp ? 0.f : vn;
            bal3  = __ballot(sp);
        }
        // masks are wave-uniform; lanes 0..7 pick their 32-bit word
        unsigned long long m01 = (w & 2) ? bal1 : bal0;
        unsigned long long m23 = (w & 2) ? bal3 : bal2;
        unsigned long long m   = (w & 4) ? m23 : m01;
        unsigned word = (unsigned)((w & 1) ? (m >> 32) : m);
        if (w < 8) s_bits[slot][w] = word;
    };

    // conv LUT compute from pre-read words -> s_p[slot]
    auto conv_compute = [&](int slot, unsigned wb0, unsigned wb1, unsigned wb2) {
        const int i0 = (wb0 >> shx)   & 31;
        const int i1 = (wb0 >> shx16) & 31;
        const int i2 = (wb1 >> shx)   & 31;
        const int i3 = (wb1 >> shx16) & 31;
        const int i4 = (wb2 >> shx)   & 31;

        const float4 f0 = s_lut[0][i0];
        const float4 f1 = s_lut[1][i1];
        const float4 f2 = s_lut[2][i2];
        const float4 f3 = s_lut[3][i3];
        const float4 g0 = s_lut[0][i1];
        const float4 g1 = s_lut[1][i2];
        const float4 g2 = s_lut[2][i3];
        const float4 g3 = s_lut[3][i4];

        v2f a00 = (v2f){f0.x, f0.y};  a00 += (v2f){f1.x, f1.y};
        a00 += (v2f){f2.x, f2.y};     a00 += (v2f){f3.x, f3.y};
        v2f a01 = (v2f){f0.z, f0.w};  a01 += (v2f){f1.z, f1.w};
        a01 += (v2f){f2.z, f2.w};     a01 += (v2f){f3.z, f3.w};
        v2f a10 = (v2f){g0.x, g0.y};  a10 += (v2f){g1.x, g1.y};
        a10 += (v2f){g2.x, g2.y};     a10 += (v2f){g3.x, g3.y};
        v2f a11 = (v2f){g0.z, g0.w};  a11 += (v2f){g1.z, g1.w};
        a11 += (v2f){g2.z, g2.w};     a11 += (v2f){g3.z, g3.w};

        v2f v00 = a00 + cb2, v01 = a01 + cb2;
        v2f v10 = a10 + cb2, v11 = a11 + cb2;
        v2f m2 = __builtin_elementwise_max(
                     __builtin_elementwise_max(v00, v01),
                     __builtin_elementwise_max(v10, v11));

        float* pbuf = s_p[slot];
        pbuf[off0]      = m2.x;   // p[w]
        pbuf[off0 + 40] = m2.y;   // p[36 + w]
    };

    // linear + decoder for step s; deferred store slot k
    auto lin_dec = [&](int s, int k) {
        const float* pp = &s_p[s & 15][lq * 20];
        float pv[18];
#pragma unroll
        for (int jj = 0; jj < 18; ++jj) pv[jj] = pp[jj];
        float partial = 0.0f;
#pragma unroll
        for (int jj = 0; jj < 18; ++jj)
            partial = fmaf(lwreg[jj], pv[jj], partial);

        // quad reduce; on lq==0 lanes the order is exactly (((p0+p1)+p2)+p3)
        float p1 = __shfl_xor(partial, 1);
        float p2 = __shfl_xor(partial, 2);
        float p3 = __shfl_xor(partial, 3);
        float lin = __fadd_rn(
            __fadd_rn(__fadd_rn(__fadd_rn(partial, p1), p2), p3), lbias);

        float vd  = __fadd_rn(v, __fmul_rn(0.1f, __fsub_rn(i_syn, v)));
        float id  = __fsub_rn(i_syn, __fmul_rn(0.2f, i_syn));
        float spk = (vd > 1.0f) ? 1.0f : 0.0f;
        v = (vd > 1.0f) ? 0.0f : vd;
        sc += spk;
        svv[k] = v;
        svs[k] = spk;
        i_syn = __fadd_rn(id, lin);
    };

    auto issue_stores = [&]() {
        if (lq == 0 && lo < 10) {
#pragma unroll
            for (int k = 0; k < 6; ++k) {
                mp[(size_t)k * BO]  = svv[k];
                spp[(size_t)k * BO] = svs[k];
            }
        }
        mp  += 6 * BO;
        spp += 6 * BO;
    };

    // ---- prologue: enc(0) -> bits[0] ----
    if (wv == 0) enc_pack(0);

    const int NG = T / 6;   // T % 6 == 0

    for (int g = 0; g < NG; ++g) {
        const int base = 6 * g;
        if (wv == 0) {
#pragma unroll
            for (int k = 0; k < 4; ++k) {
                const int s = base + k;
                unsigned wb0 = 0, wb1 = 0, wb2 = 0;
                if (convlane) {
                    const unsigned* bb = &s_bits[s & 15][wordsel];
                    wb0 = bb[0]; wb1 = bb[1]; wb2 = bb[2];
                }
                enc_pack((s + 1) & 15);              // enc hides the bit reads
                if (convlane) conv_compute(s & 15, wb0, wb1, wb2);
            }
            enc_pack((base + 5) & 15);
            enc_pack((base + 6) & 15);
        } else {
            if (g >= 2) issue_stores();              // group g-2
            if (g >= 1) {
                const int pb = base - 6;
                // conv for steps pb+4, pb+5 (bits from group g-1, barrier-safe)
                unsigned a0 = 0, a1 = 0, a2 = 0, c0 = 0, c1 = 0, c2 = 0;
                if (convlane) {
                    const unsigned* ba = &s_bits[(pb + 4) & 15][wordsel];
                    a0 = ba[0]; a1 = ba[1]; a2 = ba[2];
                    const unsigned* bc = &s_bits[(pb + 5) & 15][wordsel];
                    c0 = bc[0]; c1 = bc[1]; c2 = bc[2];
                    conv_compute((pb + 4) & 15, a0, a1, a2);
                    conv_compute((pb + 5) & 15, c0, c1, c2);
                }
#pragma unroll
                for (int k = 0; k < 6; ++k)          // lin+dec group g-1
                    lin_dec(pb + k, k);
            }
        }
        __syncthreads();
    }

    // ---- epilogue (wave1): stores NG-2, conv+lin+dec NG-1, stores NG-1 ----
    if (wv == 1) {
        issue_stores();                              // group NG-2
        const int pb = 6 * (NG - 1);
        unsigned a0 = 0, a1 = 0, a2 = 0, c0 = 0, c1 = 0, c2 = 0;
        if (convlane) {
            const unsigned* ba = &s_bits[(pb + 4) & 15][wordsel];
            a0 = ba[0]; a1 = ba[1]; a2 = ba[2];
            const unsigned* bc = &s_bits[(pb + 5) & 15][wordsel];
            c0 = bc[0]; c1 = bc[1]; c2 = bc[2];
            conv_compute((pb + 4) & 15, a0, a1, a2);
            conv_compute((pb + 5) & 15, c0, c1, c2);
        }
#pragma unroll
        for (int k = 0; k < 6; ++k)
            lin_dec(pb + k, k);
        issue_stores();                              // group NG-1
        if (lq == 0 && lo < 10) out[(size_t)b * 10 + lo] = sc;
    }
}

extern "C" void kernel_launch(void* const* d_in, const int* in_sizes, int n_in,
                              void* d_out, int out_size, void* d_ws, size_t ws_size,
                              hipStream_t stream) {
    const float* x      = (const float*)d_in[0];
    const float* conv_w = (const float*)d_in[1];
    const float* conv_b = (const float*)d_in[2];
    const float* lin_w  = (const float*)d_in[3];
    const float* lin_b  = (const float*)d_in[4];
    float* out = (float*)d_out;

    const int B = in_sizes[0] / 225;             // x is [B,1,15,15]
    const int T = (out_size / (B * 10) - 1) / 2; // out = B*10 * (1 + 2T); T=300

    snn_step_kernel<<<B, 128, 0, stream>>>(x, conv_w, conv_b, lin_w, lin_b, out, T, B);
}